// Round 5
// baseline (1891.110 us; speedup 1.0000x reference)
//
#include <hip/hip_runtime.h>
#include <math.h>

#define B_ 16
#define N_ 2048
#define D_ 1024
#define KTOP 100
#define RTOP 5
#define JCH 8
#define BM 128
#define BN 128
#define BK 16

// ---------------- Kernel A: flash-style row stats (m, l) over s = q k^T ----
__global__ __launch_bounds__(256) void rowstats_kernel(
    const float* __restrict__ q, const float* __restrict__ k,
    float* __restrict__ mpart, float* __restrict__ lpart) {
  __shared__ float As[BK][BM];
  __shared__ float Bs[BK][BN];
  __shared__ float mrow[BM];
  __shared__ float lrow[BM];
  const int tid = threadIdx.x;
  const int tx = tid & 15;
  const int ty = tid >> 4;
  const int b = blockIdx.z;
  const int row0 = blockIdx.x * BM;
  const int jc0 = blockIdx.y * (N_ / JCH);
  const float* qb = q + ((size_t)b * N_ + row0) * D_;
  const float* kb = k + (size_t)b * N_ * D_;
  if (tid < BM) { mrow[tid] = -INFINITY; lrow[tid] = 0.0f; }
  const int lr = tid >> 1;
  const int lc = (tid & 1) * 8;
  float acc[8][8];
  for (int jt = 0; jt < (N_ / JCH) / BN; ++jt) {
    const int col0 = jc0 + jt * BN;
    const float* kbj = kb + (size_t)col0 * D_;
#pragma unroll
    for (int r = 0; r < 8; ++r)
#pragma unroll
      for (int c = 0; c < 8; ++c) acc[r][c] = 0.0f;
    for (int kt = 0; kt < D_ / BK; ++kt) {
      __syncthreads();
      const float* ap = qb + (size_t)lr * D_ + kt * BK + lc;
      const float* bp = kbj + (size_t)lr * D_ + kt * BK + lc;
      float4 a0 = *(const float4*)ap;
      float4 a1 = *(const float4*)(ap + 4);
      float4 b0 = *(const float4*)bp;
      float4 b1 = *(const float4*)(bp + 4);
      As[lc + 0][lr] = a0.x; As[lc + 1][lr] = a0.y; As[lc + 2][lr] = a0.z; As[lc + 3][lr] = a0.w;
      As[lc + 4][lr] = a1.x; As[lc + 5][lr] = a1.y; As[lc + 6][lr] = a1.z; As[lc + 7][lr] = a1.w;
      Bs[lc + 0][lr] = b0.x; Bs[lc + 1][lr] = b0.y; Bs[lc + 2][lr] = b0.z; Bs[lc + 3][lr] = b0.w;
      Bs[lc + 4][lr] = b1.x; Bs[lc + 5][lr] = b1.y; Bs[lc + 6][lr] = b1.z; Bs[lc + 7][lr] = b1.w;
      __syncthreads();
#pragma unroll
      for (int kk = 0; kk < BK; ++kk) {
        float4 ar0 = *(const float4*)&As[kk][ty * 8];
        float4 ar1 = *(const float4*)&As[kk][ty * 8 + 4];
        float4 br0 = *(const float4*)&Bs[kk][tx * 8];
        float4 br1 = *(const float4*)&Bs[kk][tx * 8 + 4];
        float av[8] = {ar0.x, ar0.y, ar0.z, ar0.w, ar1.x, ar1.y, ar1.z, ar1.w};
        float bv[8] = {br0.x, br0.y, br0.z, br0.w, br1.x, br1.y, br1.z, br1.w};
#pragma unroll
        for (int r = 0; r < 8; ++r)
#pragma unroll
          for (int c = 0; c < 8; ++c) acc[r][c] = fmaf(av[r], bv[c], acc[r][c]);
      }
    }
    // online softmax stats update for this 128x128 tile
#pragma unroll
    for (int r = 0; r < 8; ++r) {
      float rm = acc[r][0];
#pragma unroll
      for (int c = 1; c < 8; ++c) rm = fmaxf(rm, acc[r][c]);
#pragma unroll
      for (int m = 1; m < 16; m <<= 1) rm = fmaxf(rm, __shfl_xor(rm, m));
      const int gr = ty * 8 + r;
      float mold = mrow[gr];
      float mnew = fmaxf(mold, rm);
      float ps = 0.0f;
#pragma unroll
      for (int c = 0; c < 8; ++c) ps += __expf(acc[r][c] - mnew);
#pragma unroll
      for (int m = 1; m < 16; m <<= 1) ps += __shfl_xor(ps, m);
      if (tx == 0) {
        lrow[gr] = lrow[gr] * __expf(mold - mnew) + ps;
        mrow[gr] = mnew;
      }
    }
  }
  __syncthreads();
  if (tid < BM) {
    size_t o = ((size_t)b * JCH + blockIdx.y) * N_ + row0 + tid;
    mpart[o] = mrow[tid];
    lpart[o] = lrow[tid];
  }
}

// ---------------- Kernel A2: combine partial (m,l) across j-chunks ---------
__global__ __launch_bounds__(256) void combine_kernel(
    const float* __restrict__ mpart, const float* __restrict__ lpart,
    float* __restrict__ mfin, float* __restrict__ lfin) {
  int r = blockIdx.x * 256 + threadIdx.x;
  int b = r >> 11;
  int i = r & (N_ - 1);
  float m = -INFINITY, l = 0.0f;
  for (int jc = 0; jc < JCH; ++jc) {
    size_t o = ((size_t)b * JCH + jc) * N_ + i;
    float mp = mpart[o], lp = lpart[o];
    float mn = fmaxf(m, mp);
    l = l * __expf(m - mn) + lp * __expf(mp - mn);
    m = mn;
  }
  mfin[r] = m;
  lfin[r] = l;
}

// ---------------- Kernel B: diagonal softmax values ------------------------
__global__ __launch_bounds__(256) void diag_kernel(
    const float* __restrict__ q, const float* __restrict__ k,
    const float* __restrict__ mfin, const float* __restrict__ lfin,
    float* __restrict__ diag) {
  int wave = threadIdx.x >> 6, lane = threadIdx.x & 63;
  int row = blockIdx.x * 4 + wave;  // 0 .. B_*N_-1
  int b = row >> 11, i = row & (N_ - 1);
  const float* qr = q + ((size_t)b * N_ + i) * D_;
  const float* kr = k + ((size_t)b * N_ + i) * D_;
  float s = 0.0f;
  for (int t = 0; t < D_ / 64; ++t) s = fmaf(qr[lane + (t << 6)], kr[lane + (t << 6)], s);
  for (int m = 1; m < 64; m <<= 1) s += __shfl_xor(s, m);
  if (lane == 0) diag[row] = __expf(s - mfin[row]) / lfin[row];
}

// ---------------- Kernel C: per-batch top-100 of diag, sorted ascending ----
__global__ __launch_bounds__(256) void top100_kernel(
    const float* __restrict__ diag, int* __restrict__ inst_idx) {
  __shared__ float sval[N_];
  __shared__ int sidx[N_];
  __shared__ int top[128];
  int b = blockIdx.x, tid = threadIdx.x;
  for (int i = tid; i < N_; i += 256) { sval[i] = diag[(size_t)b * N_ + i]; sidx[i] = i; }
  __syncthreads();
  // bitonic sort: value descending, tie -> lower index first (lax.top_k order)
  for (int ksz = 2; ksz <= N_; ksz <<= 1) {
    for (int j = ksz >> 1; j > 0; j >>= 1) {
      for (int t = tid; t < N_; t += 256) {
        int x = t ^ j;
        if (x > t) {
          float va = sval[t], vb = sval[x];
          int ia = sidx[t], ib = sidx[x];
          bool agtb = (va > vb) || (va == vb && ia < ib);
          bool up = ((t & ksz) == 0);
          if (up != agtb) { sval[t] = vb; sval[x] = va; sidx[t] = ib; sidx[x] = ia; }
        }
      }
      __syncthreads();
    }
  }
  if (tid < 128) top[tid] = (tid < KTOP) ? sidx[tid] : 0x7FFFFFFF;
  __syncthreads();
  // sort the 100 winners' indices ascending (bitonic over 128 with +inf pad)
  for (int ksz = 2; ksz <= 128; ksz <<= 1) {
    for (int j = ksz >> 1; j > 0; j >>= 1) {
      if (tid < 128) {
        int t = tid, x = t ^ j;
        if (x > t) {
          int ia = top[t], ib = top[x];
          bool up = ((t & ksz) == 0);
          bool altb = ia < ib;
          if (up != altb) { top[t] = ib; top[x] = ia; }
        }
      }
      __syncthreads();
    }
  }
  if (tid < KTOP) inst_idx[b * KTOP + tid] = top[tid];
}

// ---------------- Kernel D: rel 100x100, mask diag, top-5 per row ----------
__global__ __launch_bounds__(256) void reltop_kernel(
    const float* __restrict__ q, const float* __restrict__ k,
    const float* __restrict__ mfin, const float* __restrict__ lfin,
    const int* __restrict__ inst_idx, float* __restrict__ out0,
    int* __restrict__ pairs) {
  __shared__ int inst[KTOP];
  __shared__ float qv[D_];
  __shared__ float sv[KTOP];
  int a = blockIdx.x, b = blockIdx.y, tid = threadIdx.x;
  if (tid < KTOP) inst[tid] = inst_idx[b * KTOP + tid];
  __syncthreads();
  int ia = inst[a];
  const float* qrow = q + ((size_t)b * N_ + ia) * D_;
  for (int t = tid; t < D_; t += 256) qv[t] = qrow[t];
  __syncthreads();
  int wave = tid >> 6, lane = tid & 63;
  for (int c0 = 0; c0 < KTOP; c0 += 4) {
    int c = c0 + wave;
    const float* krow = k + ((size_t)b * N_ + inst[c]) * D_;
    float s = 0.0f;
    for (int t = 0; t < D_ / 64; ++t) s = fmaf(qv[lane + (t << 6)], krow[lane + (t << 6)], s);
    for (int m = 1; m < 64; m <<= 1) s += __shfl_xor(s, m);
    if (lane == 0) sv[c] = s;
  }
  __syncthreads();
  if (tid < 64) {
    float mi = mfin[(size_t)b * N_ + ia];
    float li = lfin[(size_t)b * N_ + ia];
    float c0v = (tid == a) ? 1e9f : __expf(sv[tid] - mi) / li;
    int c0i = tid;
    float c1v = -1.0f;
    int c1i = 1 << 20;
    if (tid + 64 < KTOP) {
      c1v = (tid + 64 == a) ? 1e9f : __expf(sv[tid + 64] - mi) / li;
      c1i = tid + 64;
    }
    int sel[RTOP];
    for (int rr = 0; rr < RTOP; ++rr) {
      float v;
      int idx;
      if (c1v > c0v || (c1v == c0v && c1i < c0i)) { v = c1v; idx = c1i; }
      else { v = c0v; idx = c0i; }
      for (int m = 1; m < 64; m <<= 1) {
        float ov = __shfl_xor(v, m);
        int oi = __shfl_xor(idx, m);
        if (ov > v || (ov == v && oi < idx)) { v = ov; idx = oi; }
      }
      sel[rr] = idx;
      if (idx == c0i) c0v = -2.0f;
      if (idx == c1i) c1v = -2.0f;
    }
    if (lane == 0) {
      for (int i2 = 0; i2 < RTOP; ++i2)
        for (int j2 = 0; j2 < RTOP - 1 - i2; ++j2)
          if (sel[j2] > sel[j2 + 1]) { int tswap = sel[j2]; sel[j2] = sel[j2 + 1]; sel[j2 + 1] = tswap; }
      for (int rr = 0; rr < RTOP; ++rr) {
        size_t ri = (size_t)b * KTOP * RTOP + (size_t)a * RTOP + rr;
        out0[ri * 3 + 0] = (float)b;
        out0[ri * 3 + 1] = (float)ia;
        out0[ri * 3 + 2] = (float)inst[sel[rr]];
        pairs[ri * 2 + 0] = ia;
        pairs[ri * 2 + 1] = inst[sel[rr]];
      }
    }
  }
}

// ---------------- Kernel E: gather + add + LayerNorm -----------------------
__global__ __launch_bounds__(256) void embed_kernel(
    const float* __restrict__ q, const int* __restrict__ pairs,
    float* __restrict__ out1) {
  __shared__ float red[8];
  int r = blockIdx.x, b = blockIdx.y, tid = threadIdx.x;
  size_t ri = (size_t)b * KTOP * RTOP + r;
  int subj = pairs[ri * 2 + 0], obj = pairs[ri * 2 + 1];
  const float* qs = q + ((size_t)b * N_ + subj) * D_;
  const float* qo = q + ((size_t)b * N_ + obj) * D_;
  float4 v1 = *(const float4*)(qs + tid * 4);
  float4 v2 = *(const float4*)(qo + tid * 4);
  float x0 = v1.x + v2.x, x1 = v1.y + v2.y, x2 = v1.z + v2.z, x3 = v1.w + v2.w;
  float s = x0 + x1 + x2 + x3;
  float qq = x0 * x0 + x1 * x1 + x2 * x2 + x3 * x3;
  int lane = tid & 63, wave = tid >> 6;
  for (int m = 1; m < 64; m <<= 1) { s += __shfl_xor(s, m); qq += __shfl_xor(qq, m); }
  if (lane == 0) { red[wave] = s; red[4 + wave] = qq; }
  __syncthreads();
  float S = red[0] + red[1] + red[2] + red[3];
  float Q = red[4] + red[5] + red[6] + red[7];
  float mu = S * (1.0f / D_);
  float var = Q * (1.0f / D_) - mu * mu;
  float rstd = 1.0f / sqrtf(var + 1e-5f);
  float4 o;
  o.x = (x0 - mu) * rstd;
  o.y = (x1 - mu) * rstd;
  o.z = (x2 - mu) * rstd;
  o.w = (x3 - mu) * rstd;
  *(float4*)(out1 + ri * D_ + tid * 4) = o;
}

extern "C" void kernel_launch(void* const* d_in, const int* in_sizes, int n_in,
                              void* d_out, int out_size, void* d_ws, size_t ws_size,
                              hipStream_t stream) {
  (void)in_sizes; (void)n_in; (void)out_size; (void)ws_size;
  const float* q = (const float*)d_in[0];
  const float* k = (const float*)d_in[1];
  float* out = (float*)d_out;

  char* ws = (char*)d_ws;
  float* mpart = (float*)ws; ws += (size_t)B_ * JCH * N_ * 4;
  float* lpart = (float*)ws; ws += (size_t)B_ * JCH * N_ * 4;
  float* mfin = (float*)ws;  ws += (size_t)B_ * N_ * 4;
  float* lfin = (float*)ws;  ws += (size_t)B_ * N_ * 4;
  float* diag = (float*)ws;  ws += (size_t)B_ * N_ * 4;
  int* inst = (int*)ws;      ws += (size_t)B_ * KTOP * 4;
  int* pairs = (int*)ws;     // B_*KTOP*RTOP*2 ints

  hipLaunchKernelGGL(rowstats_kernel, dim3(N_ / BM, JCH, B_), dim3(256), 0, stream,
                     q, k, mpart, lpart);
  hipLaunchKernelGGL(combine_kernel, dim3(B_ * N_ / 256), dim3(256), 0, stream,
                     mpart, lpart, mfin, lfin);
  hipLaunchKernelGGL(diag_kernel, dim3(B_ * N_ / 4), dim3(256), 0, stream,
                     q, k, mfin, lfin, diag);
  hipLaunchKernelGGL(top100_kernel, dim3(B_), dim3(256), 0, stream, diag, inst);
  hipLaunchKernelGGL(reltop_kernel, dim3(KTOP, B_), dim3(256), 0, stream,
                     q, k, mfin, lfin, inst, out, pairs);
  hipLaunchKernelGGL(embed_kernel, dim3(KTOP * RTOP, B_), dim3(256), 0, stream,
                     q, pairs, out + (size_t)B_ * KTOP * RTOP * 3);
}

// Round 6
// 1234.134 us; speedup vs baseline: 1.5323x; 1.5323x over previous
//
#include <hip/hip_runtime.h>
#include <math.h>

#define B_ 16
#define N_ 2048
#define D_ 1024
#define KTOP 100
#define RTOP 5
#define JCH 16

typedef __attribute__((ext_vector_type(8))) short short8;
typedef __attribute__((ext_vector_type(4))) float f32x4;

__device__ inline unsigned short f2bf_rn(float x) {
  unsigned u = __float_as_uint(x);
  unsigned r = u + 0x7FFFu + ((u >> 16) & 1u);
  return (unsigned short)(r >> 16);
}
__device__ inline float bf2f(unsigned short h) {
  return __uint_as_float(((unsigned)h) << 16);
}

// ---------------- Kernel A: MFMA row stats (m, l) over s = q k^T -----------
// 3-way bf16 split per operand (h+m+l), 6 MFMA products kept -> s error ~2e-6.
// 128x128 tile per block; 4 waves, each 32 rows x 128 cols.
__global__ __launch_bounds__(256) void rowstats_mfma(
    const float* __restrict__ q, const float* __restrict__ k,
    float* __restrict__ mpart, float* __restrict__ lpart) {
  __shared__ short Ah[128 * 32], Am[128 * 32], Al[128 * 32];
  __shared__ short Bh[128 * 32], Bm[128 * 32], Bl[128 * 32];
  const int tid = threadIdx.x;
  const int wave = tid >> 6, lane = tid & 63;
  const int b = blockIdx.z;
  const int rb = blockIdx.x;   // row block (q)
  const int cb = blockIdx.y;   // col block (k) == j-chunk
  const float* qb = q + ((size_t)b * N_ + rb * 128) * D_;
  const float* kb = k + ((size_t)b * N_ + cb * 128) * D_;

  // staging role: threads 0-127 stage q rows, 128-255 stage k rows
  const int srow = tid & 127;
  const float* sbase = ((tid < 128) ? qb : kb) + (size_t)srow * D_;
  short* dsth = (tid < 128) ? Ah : Bh;
  short* dstm = (tid < 128) ? Am : Bm;
  short* dstl = (tid < 128) ? Al : Bl;
  const int swz = (srow >> 1) & 3;

  f32x4 acc[2][8];
#pragma unroll
  for (int fr = 0; fr < 2; ++fr)
#pragma unroll
    for (int fc = 0; fc < 8; ++fc)
#pragma unroll
      for (int r = 0; r < 4; ++r) acc[fr][fc][r] = 0.0f;

  const int g = lane >> 4;      // K slot group (8 bf16 = 16B)
  const int rlo = lane & 15;    // token row within fragment

  for (int kt = 0; kt < D_ / 32; ++kt) {
    __syncthreads();  // previous tile fully consumed
    // ---- stage: load 32 f32 of this row's K-window, 3-way split to LDS ----
    {
      const float* src = sbase + kt * 32;
      float e[32];
#pragma unroll
      for (int i = 0; i < 8; ++i) {
        float4 t = ((const float4*)src)[i];
        e[4 * i + 0] = t.x; e[4 * i + 1] = t.y; e[4 * i + 2] = t.z; e[4 * i + 3] = t.w;
      }
#pragma unroll
      for (int j = 0; j < 4; ++j) {
        short8 hv, mv, lv;
#pragma unroll
        for (int u = 0; u < 8; ++u) {
          float x = e[j * 8 + u];
          unsigned short h = f2bf_rn(x);
          float xm = x - bf2f(h);
          unsigned short m = f2bf_rn(xm);
          float xl = xm - bf2f(m);
          unsigned short l = f2bf_rn(xl);
          hv[u] = (short)h; mv[u] = (short)m; lv[u] = (short)l;
        }
        const int off = srow * 32 + ((j ^ swz) << 3);
        *(short8*)(dsth + off) = hv;
        *(short8*)(dstm + off) = mv;
        *(short8*)(dstl + off) = lv;
      }
    }
    __syncthreads();  // tile ready
    // ---- compute: 2 row-frags x 8 col-frags x 6 products ----
    short8 afh[2], afm[2], afl[2];
#pragma unroll
    for (int fr = 0; fr < 2; ++fr) {
      const int R = (wave << 5) + (fr << 4) + rlo;
      const int off = R * 32 + ((g ^ ((R >> 1) & 3)) << 3);
      afh[fr] = *(const short8*)&Ah[off];
      afm[fr] = *(const short8*)&Am[off];
      afl[fr] = *(const short8*)&Al[off];
    }
#pragma unroll
    for (int fc = 0; fc < 8; ++fc) {
      const int Rb = (fc << 4) + rlo;
      const int offb = Rb * 32 + ((g ^ ((Rb >> 1) & 3)) << 3);
      short8 bh = *(const short8*)&Bh[offb];
      short8 bm = *(const short8*)&Bm[offb];
      short8 bl = *(const short8*)&Bl[offb];
#pragma unroll
      for (int fr = 0; fr < 2; ++fr) {
        acc[fr][fc] = __builtin_amdgcn_mfma_f32_16x16x32_bf16(afh[fr], bh, acc[fr][fc], 0, 0, 0);
        acc[fr][fc] = __builtin_amdgcn_mfma_f32_16x16x32_bf16(afh[fr], bm, acc[fr][fc], 0, 0, 0);
        acc[fr][fc] = __builtin_amdgcn_mfma_f32_16x16x32_bf16(afm[fr], bh, acc[fr][fc], 0, 0, 0);
        acc[fr][fc] = __builtin_amdgcn_mfma_f32_16x16x32_bf16(afm[fr], bm, acc[fr][fc], 0, 0, 0);
        acc[fr][fc] = __builtin_amdgcn_mfma_f32_16x16x32_bf16(afh[fr], bl, acc[fr][fc], 0, 0, 0);
        acc[fr][fc] = __builtin_amdgcn_mfma_f32_16x16x32_bf16(afl[fr], bh, acc[fr][fc], 0, 0, 0);
      }
    }
  }

  // ---- epilogue: per-row max & exp-sum over this 128-col chunk ----
  // C/D layout: col = lane&15, row = (lane>>4)*4 + reg  (within 16x16 frag)
#pragma unroll
  for (int fr = 0; fr < 2; ++fr) {
#pragma unroll
    for (int r = 0; r < 4; ++r) {
      float vmax = acc[fr][0][r];
#pragma unroll
      for (int fc = 1; fc < 8; ++fc) vmax = fmaxf(vmax, acc[fr][fc][r]);
#pragma unroll
      for (int m = 1; m < 16; m <<= 1) vmax = fmaxf(vmax, __shfl_xor(vmax, m));
      float s = 0.0f;
#pragma unroll
      for (int fc = 0; fc < 8; ++fc) s += __expf(acc[fr][fc][r] - vmax);
#pragma unroll
      for (int m = 1; m < 16; m <<= 1) s += __shfl_xor(s, m);
      if ((lane & 15) == 0) {
        const int row = (wave << 5) + (fr << 4) + ((lane >> 4) << 2) + r;
        size_t o = ((size_t)b * JCH + cb) * N_ + rb * 128 + row;
        mpart[o] = vmax;
        lpart[o] = s;
      }
    }
  }
}

// ---------------- Kernel A2: combine partial (m,l) across j-chunks ---------
__global__ __launch_bounds__(256) void combine_kernel(
    const float* __restrict__ mpart, const float* __restrict__ lpart,
    float* __restrict__ mfin, float* __restrict__ lfin) {
  int r = blockIdx.x * 256 + threadIdx.x;
  int b = r >> 11;
  int i = r & (N_ - 1);
  float m = -INFINITY, l = 0.0f;
  for (int jc = 0; jc < JCH; ++jc) {
    size_t o = ((size_t)b * JCH + jc) * N_ + i;
    float mp = mpart[o], lp = lpart[o];
    float mn = fmaxf(m, mp);
    l = l * __expf(m - mn) + lp * __expf(mp - mn);
    m = mn;
  }
  mfin[r] = m;
  lfin[r] = l;
}

// ---------------- Kernel B: diagonal softmax values ------------------------
__global__ __launch_bounds__(256) void diag_kernel(
    const float* __restrict__ q, const float* __restrict__ k,
    const float* __restrict__ mfin, const float* __restrict__ lfin,
    float* __restrict__ diag) {
  int wave = threadIdx.x >> 6, lane = threadIdx.x & 63;
  int row = blockIdx.x * 4 + wave;  // 0 .. B_*N_-1
  int b = row >> 11, i = row & (N_ - 1);
  const float* qr = q + ((size_t)b * N_ + i) * D_;
  const float* kr = k + ((size_t)b * N_ + i) * D_;
  float s = 0.0f;
  for (int t = 0; t < D_ / 64; ++t) s = fmaf(qr[lane + (t << 6)], kr[lane + (t << 6)], s);
  for (int m = 1; m < 64; m <<= 1) s += __shfl_xor(s, m);
  if (lane == 0) diag[row] = __expf(s - mfin[row]) / lfin[row];
}

// ---------------- Kernel C: per-batch top-100 of diag, sorted ascending ----
__global__ __launch_bounds__(256) void top100_kernel(
    const float* __restrict__ diag, int* __restrict__ inst_idx) {
  __shared__ float sval[N_];
  __shared__ int sidx[N_];
  __shared__ int top[128];
  int b = blockIdx.x, tid = threadIdx.x;
  for (int i = tid; i < N_; i += 256) { sval[i] = diag[(size_t)b * N_ + i]; sidx[i] = i; }
  __syncthreads();
  // bitonic sort: value descending, tie -> lower index first (lax.top_k order)
  for (int ksz = 2; ksz <= N_; ksz <<= 1) {
    for (int j = ksz >> 1; j > 0; j >>= 1) {
      for (int t = tid; t < N_; t += 256) {
        int x = t ^ j;
        if (x > t) {
          float va = sval[t], vb = sval[x];
          int ia = sidx[t], ib = sidx[x];
          bool agtb = (va > vb) || (va == vb && ia < ib);
          bool up = ((t & ksz) == 0);
          if (up != agtb) { sval[t] = vb; sval[x] = va; sidx[t] = ib; sidx[x] = ia; }
        }
      }
      __syncthreads();
    }
  }
  if (tid < 128) top[tid] = (tid < KTOP) ? sidx[tid] : 0x7FFFFFFF;
  __syncthreads();
  // sort the 100 winners' indices ascending (bitonic over 128 with +inf pad)
  for (int ksz = 2; ksz <= 128; ksz <<= 1) {
    for (int j = ksz >> 1; j > 0; j >>= 1) {
      if (tid < 128) {
        int t = tid, x = t ^ j;
        if (x > t) {
          int ia = top[t], ib = top[x];
          bool up = ((t & ksz) == 0);
          bool altb = ia < ib;
          if (up != altb) { top[t] = ib; top[x] = ia; }
        }
      }
      __syncthreads();
    }
  }
  if (tid < KTOP) inst_idx[b * KTOP + tid] = top[tid];
}

// ---------------- Kernel D: rel 100x100, mask diag, top-5 per row ----------
__global__ __launch_bounds__(256) void reltop_kernel(
    const float* __restrict__ q, const float* __restrict__ k,
    const float* __restrict__ mfin, const float* __restrict__ lfin,
    const int* __restrict__ inst_idx, float* __restrict__ out0,
    int* __restrict__ pairs) {
  __shared__ int inst[KTOP];
  __shared__ float qv[D_];
  __shared__ float sv[KTOP];
  int a = blockIdx.x, b = blockIdx.y, tid = threadIdx.x;
  if (tid < KTOP) inst[tid] = inst_idx[b * KTOP + tid];
  __syncthreads();
  int ia = inst[a];
  const float* qrow = q + ((size_t)b * N_ + ia) * D_;
  for (int t = tid; t < D_; t += 256) qv[t] = qrow[t];
  __syncthreads();
  int wave = tid >> 6, lane = tid & 63;
  for (int c0 = 0; c0 < KTOP; c0 += 4) {
    int c = c0 + wave;
    const float* krow = k + ((size_t)b * N_ + inst[c]) * D_;
    float s = 0.0f;
    for (int t = 0; t < D_ / 64; ++t) s = fmaf(qv[lane + (t << 6)], krow[lane + (t << 6)], s);
    for (int m = 1; m < 64; m <<= 1) s += __shfl_xor(s, m);
    if (lane == 0) sv[c] = s;
  }
  __syncthreads();
  if (tid < 64) {
    float mi = mfin[(size_t)b * N_ + ia];
    float li = lfin[(size_t)b * N_ + ia];
    float c0v = (tid == a) ? 1e9f : __expf(sv[tid] - mi) / li;
    int c0i = tid;
    float c1v = -1.0f;
    int c1i = 1 << 20;
    if (tid + 64 < KTOP) {
      c1v = (tid + 64 == a) ? 1e9f : __expf(sv[tid + 64] - mi) / li;
      c1i = tid + 64;
    }
    int sel[RTOP];
    for (int rr = 0; rr < RTOP; ++rr) {
      float v;
      int idx;
      if (c1v > c0v || (c1v == c0v && c1i < c0i)) { v = c1v; idx = c1i; }
      else { v = c0v; idx = c0i; }
      for (int m = 1; m < 64; m <<= 1) {
        float ov = __shfl_xor(v, m);
        int oi = __shfl_xor(idx, m);
        if (ov > v || (ov == v && oi < idx)) { v = ov; idx = oi; }
      }
      sel[rr] = idx;
      if (idx == c0i) c0v = -2.0f;
      if (idx == c1i) c1v = -2.0f;
    }
    if (lane == 0) {
      for (int i2 = 0; i2 < RTOP; ++i2)
        for (int j2 = 0; j2 < RTOP - 1 - i2; ++j2)
          if (sel[j2] > sel[j2 + 1]) { int tswap = sel[j2]; sel[j2] = sel[j2 + 1]; sel[j2 + 1] = tswap; }
      for (int rr = 0; rr < RTOP; ++rr) {
        size_t ri = (size_t)b * KTOP * RTOP + (size_t)a * RTOP + rr;
        out0[ri * 3 + 0] = (float)b;
        out0[ri * 3 + 1] = (float)ia;
        out0[ri * 3 + 2] = (float)inst[sel[rr]];
        pairs[ri * 2 + 0] = ia;
        pairs[ri * 2 + 1] = inst[sel[rr]];
      }
    }
  }
}

// ---------------- Kernel E: gather + add + LayerNorm -----------------------
__global__ __launch_bounds__(256) void embed_kernel(
    const float* __restrict__ q, const int* __restrict__ pairs,
    float* __restrict__ out1) {
  __shared__ float red[8];
  int r = blockIdx.x, b = blockIdx.y, tid = threadIdx.x;
  size_t ri = (size_t)b * KTOP * RTOP + r;
  int subj = pairs[ri * 2 + 0], obj = pairs[ri * 2 + 1];
  const float* qs = q + ((size_t)b * N_ + subj) * D_;
  const float* qo = q + ((size_t)b * N_ + obj) * D_;
  float4 v1 = *(const float4*)(qs + tid * 4);
  float4 v2 = *(const float4*)(qo + tid * 4);
  float x0 = v1.x + v2.x, x1 = v1.y + v2.y, x2 = v1.z + v2.z, x3 = v1.w + v2.w;
  float s = x0 + x1 + x2 + x3;
  float qq = x0 * x0 + x1 * x1 + x2 * x2 + x3 * x3;
  int lane = tid & 63, wave = tid >> 6;
  for (int m = 1; m < 64; m <<= 1) { s += __shfl_xor(s, m); qq += __shfl_xor(qq, m); }
  if (lane == 0) { red[wave] = s; red[4 + wave] = qq; }
  __syncthreads();
  float S = red[0] + red[1] + red[2] + red[3];
  float Q = red[4] + red[5] + red[6] + red[7];
  float mu = S * (1.0f / D_);
  float var = Q * (1.0f / D_) - mu * mu;
  float rstd = 1.0f / sqrtf(var + 1e-5f);
  float4 o;
  o.x = (x0 - mu) * rstd;
  o.y = (x1 - mu) * rstd;
  o.z = (x2 - mu) * rstd;
  o.w = (x3 - mu) * rstd;
  *(float4*)(out1 + ri * D_ + tid * 4) = o;
}

extern "C" void kernel_launch(void* const* d_in, const int* in_sizes, int n_in,
                              void* d_out, int out_size, void* d_ws, size_t ws_size,
                              hipStream_t stream) {
  (void)in_sizes; (void)n_in; (void)out_size; (void)ws_size;
  const float* q = (const float*)d_in[0];
  const float* k = (const float*)d_in[1];
  float* out = (float*)d_out;

  char* ws = (char*)d_ws;
  float* mpart = (float*)ws; ws += (size_t)B_ * JCH * N_ * 4;
  float* lpart = (float*)ws; ws += (size_t)B_ * JCH * N_ * 4;
  float* mfin = (float*)ws;  ws += (size_t)B_ * N_ * 4;
  float* lfin = (float*)ws;  ws += (size_t)B_ * N_ * 4;
  float* diag = (float*)ws;  ws += (size_t)B_ * N_ * 4;
  int* inst = (int*)ws;      ws += (size_t)B_ * KTOP * 4;
  int* pairs = (int*)ws;     // B_*KTOP*RTOP*2 ints

  hipLaunchKernelGGL(rowstats_mfma, dim3(N_ / 128, N_ / 128, B_), dim3(256), 0, stream,
                     q, k, mpart, lpart);
  hipLaunchKernelGGL(combine_kernel, dim3(B_ * N_ / 256), dim3(256), 0, stream,
                     mpart, lpart, mfin, lfin);
  hipLaunchKernelGGL(diag_kernel, dim3(B_ * N_ / 4), dim3(256), 0, stream,
                     q, k, mfin, lfin, diag);
  hipLaunchKernelGGL(top100_kernel, dim3(B_), dim3(256), 0, stream, diag, inst);
  hipLaunchKernelGGL(reltop_kernel, dim3(KTOP, B_), dim3(256), 0, stream,
                     q, k, mfin, lfin, inst, out, pairs);
  hipLaunchKernelGGL(embed_kernel, dim3(KTOP * RTOP, B_), dim3(256), 0, stream,
                     q, pairs, out + (size_t)B_ * KTOP * RTOP * 3);
}

// Round 8
// 1100.285 us; speedup vs baseline: 1.7187x; 1.1216x over previous
//
#include <hip/hip_runtime.h>
#include <math.h>

#define B_ 16
#define N_ 2048
#define D_ 1024
#define KTOP 100
#define RTOP 5
#define JCH 16

typedef __attribute__((ext_vector_type(8))) short short8;
typedef __attribute__((ext_vector_type(4))) float f32x4;

__device__ inline unsigned cvt_pk_bf16(float lo, float hi) {
  unsigned r;
  asm("v_cvt_pk_bf16_f32 %0, %1, %2" : "=v"(r) : "v"(lo), "v"(hi));
  return r;
}
__device__ inline float lo_bf(unsigned p) { return __uint_as_float(p << 16); }
__device__ inline float hi_bf(unsigned p) { return __uint_as_float(p & 0xFFFF0000u); }

// ---------------- Kernel A: MFMA row stats (m, l) over s = q k^T -----------
// 3-way bf16 split per operand (h+m+l), 6 MFMA products kept -> s error ~2e-6.
// 128x128 tile per block; 4 waves, each 32 rows x 128 cols.
// Staging uses v_cvt_pk_bf16_f32 (packed u32 == LDS short8 format directly).
__global__ __launch_bounds__(256) void rowstats_mfma(
    const float* __restrict__ q, const float* __restrict__ k,
    float* __restrict__ mpart, float* __restrict__ lpart) {
  __shared__ short Ah[128 * 32], Am[128 * 32], Al[128 * 32];
  __shared__ short Bh[128 * 32], Bm[128 * 32], Bl[128 * 32];
  const int tid = threadIdx.x;
  const int wave = tid >> 6, lane = tid & 63;
  const int b = blockIdx.z;
  const int rb = blockIdx.x;   // row block (q)
  const int cb = blockIdx.y;   // col block (k) == j-chunk
  const float* qb = q + ((size_t)b * N_ + rb * 128) * D_;
  const float* kb = k + ((size_t)b * N_ + cb * 128) * D_;

  // staging role: threads 0-127 stage q rows, 128-255 stage k rows
  const int srow = tid & 127;
  const float* sbase = ((tid < 128) ? qb : kb) + (size_t)srow * D_;
  short* dsth = (tid < 128) ? Ah : Bh;
  short* dstm = (tid < 128) ? Am : Bm;
  short* dstl = (tid < 128) ? Al : Bl;
  const int swz = (srow >> 1) & 3;

  f32x4 acc[2][8];
#pragma unroll
  for (int fr = 0; fr < 2; ++fr)
#pragma unroll
    for (int fc = 0; fc < 8; ++fc)
#pragma unroll
      for (int r = 0; r < 4; ++r) acc[fr][fc][r] = 0.0f;

  const int g = lane >> 4;      // K slot group (8 bf16 = 16B)
  const int rlo = lane & 15;    // token row within fragment

  for (int kt = 0; kt < D_ / 32; ++kt) {
    __syncthreads();  // previous tile fully consumed
    // ---- stage: load 32 f32 of this row's K-window, 3-way split to LDS ----
    {
      const float* src = sbase + kt * 32;
#pragma unroll
      for (int j = 0; j < 4; ++j) {
        float4 ta = ((const float4*)src)[2 * j];
        float4 tb = ((const float4*)src)[2 * j + 1];
        // level h
        unsigned h0 = cvt_pk_bf16(ta.x, ta.y);
        unsigned h1 = cvt_pk_bf16(ta.z, ta.w);
        unsigned h2 = cvt_pk_bf16(tb.x, tb.y);
        unsigned h3 = cvt_pk_bf16(tb.z, tb.w);
        // residual r = x - h  (exact)
        float r0 = ta.x - lo_bf(h0), r1 = ta.y - hi_bf(h0);
        float r2 = ta.z - lo_bf(h1), r3 = ta.w - hi_bf(h1);
        float r4 = tb.x - lo_bf(h2), r5 = tb.y - hi_bf(h2);
        float r6 = tb.z - lo_bf(h3), r7 = tb.w - hi_bf(h3);
        // level m
        unsigned m0 = cvt_pk_bf16(r0, r1);
        unsigned m1 = cvt_pk_bf16(r2, r3);
        unsigned m2 = cvt_pk_bf16(r4, r5);
        unsigned m3 = cvt_pk_bf16(r6, r7);
        // residual s = r - m (exact)
        float s0 = r0 - lo_bf(m0), s1 = r1 - hi_bf(m0);
        float s2 = r2 - lo_bf(m1), s3 = r3 - hi_bf(m1);
        float s4 = r4 - lo_bf(m2), s5 = r5 - hi_bf(m2);
        float s6 = r6 - lo_bf(m3), s7 = r7 - hi_bf(m3);
        // level l
        unsigned l0 = cvt_pk_bf16(s0, s1);
        unsigned l1 = cvt_pk_bf16(s2, s3);
        unsigned l2 = cvt_pk_bf16(s4, s5);
        unsigned l3 = cvt_pk_bf16(s6, s7);
        const int off = srow * 32 + ((j ^ swz) << 3);
        *(int4*)(dsth + off) = make_int4(h0, h1, h2, h3);
        *(int4*)(dstm + off) = make_int4(m0, m1, m2, m3);
        *(int4*)(dstl + off) = make_int4(l0, l1, l2, l3);
      }
    }
    __syncthreads();  // tile ready
    // ---- compute: 2 row-frags x 8 col-frags x 6 products ----
    short8 afh[2], afm[2], afl[2];
#pragma unroll
    for (int fr = 0; fr < 2; ++fr) {
      const int R = (wave << 5) + (fr << 4) + rlo;
      const int off = R * 32 + ((g ^ ((R >> 1) & 3)) << 3);
      afh[fr] = *(const short8*)&Ah[off];
      afm[fr] = *(const short8*)&Am[off];
      afl[fr] = *(const short8*)&Al[off];
    }
#pragma unroll
    for (int fc = 0; fc < 8; ++fc) {
      const int Rb = (fc << 4) + rlo;
      const int offb = Rb * 32 + ((g ^ ((Rb >> 1) & 3)) << 3);
      short8 bh = *(const short8*)&Bh[offb];
      short8 bm = *(const short8*)&Bm[offb];
      short8 bl = *(const short8*)&Bl[offb];
#pragma unroll
      for (int fr = 0; fr < 2; ++fr) {
        acc[fr][fc] = __builtin_amdgcn_mfma_f32_16x16x32_bf16(afh[fr], bh, acc[fr][fc], 0, 0, 0);
        acc[fr][fc] = __builtin_amdgcn_mfma_f32_16x16x32_bf16(afh[fr], bm, acc[fr][fc], 0, 0, 0);
        acc[fr][fc] = __builtin_amdgcn_mfma_f32_16x16x32_bf16(afm[fr], bh, acc[fr][fc], 0, 0, 0);
        acc[fr][fc] = __builtin_amdgcn_mfma_f32_16x16x32_bf16(afm[fr], bm, acc[fr][fc], 0, 0, 0);
        acc[fr][fc] = __builtin_amdgcn_mfma_f32_16x16x32_bf16(afh[fr], bl, acc[fr][fc], 0, 0, 0);
        acc[fr][fc] = __builtin_amdgcn_mfma_f32_16x16x32_bf16(afl[fr], bh, acc[fr][fc], 0, 0, 0);
      }
    }
  }

  // ---- epilogue: per-row max & exp-sum over this 128-col chunk ----
  // C/D layout: col = lane&15, row = (lane>>4)*4 + reg  (within 16x16 frag)
#pragma unroll
  for (int fr = 0; fr < 2; ++fr) {
#pragma unroll
    for (int r = 0; r < 4; ++r) {
      float vmax = acc[fr][0][r];
#pragma unroll
      for (int fc = 1; fc < 8; ++fc) vmax = fmaxf(vmax, acc[fr][fc][r]);
#pragma unroll
      for (int m = 1; m < 16; m <<= 1) vmax = fmaxf(vmax, __shfl_xor(vmax, m));
      float s = 0.0f;
#pragma unroll
      for (int fc = 0; fc < 8; ++fc) s += __expf(acc[fr][fc][r] - vmax);
#pragma unroll
      for (int m = 1; m < 16; m <<= 1) s += __shfl_xor(s, m);
      if ((lane & 15) == 0) {
        const int row = (wave << 5) + (fr << 4) + ((lane >> 4) << 2) + r;
        size_t o = ((size_t)b * JCH + cb) * N_ + rb * 128 + row;
        mpart[o] = vmax;
        lpart[o] = s;
      }
    }
  }
}

// ---------------- Kernel A2: combine partial (m,l) across j-chunks ---------
__global__ __launch_bounds__(256) void combine_kernel(
    const float* __restrict__ mpart, const float* __restrict__ lpart,
    float* __restrict__ mfin, float* __restrict__ lfin) {
  int r = blockIdx.x * 256 + threadIdx.x;
  int b = r >> 11;
  int i = r & (N_ - 1);
  float m = -INFINITY, l = 0.0f;
  for (int jc = 0; jc < JCH; ++jc) {
    size_t o = ((size_t)b * JCH + jc) * N_ + i;
    float mp = mpart[o], lp = lpart[o];
    float mn = fmaxf(m, mp);
    l = l * __expf(m - mn) + lp * __expf(mp - mn);
    m = mn;
  }
  mfin[r] = m;
  lfin[r] = l;
}

// ---------------- Kernel B: diagonal softmax values ------------------------
__global__ __launch_bounds__(256) void diag_kernel(
    const float* __restrict__ q, const float* __restrict__ k,
    const float* __restrict__ mfin, const float* __restrict__ lfin,
    float* __restrict__ diag) {
  int wave = threadIdx.x >> 6, lane = threadIdx.x & 63;
  int row = blockIdx.x * 4 + wave;  // 0 .. B_*N_-1
  int b = row >> 11, i = row & (N_ - 1);
  const float* qr = q + ((size_t)b * N_ + i) * D_;
  const float* kr = k + ((size_t)b * N_ + i) * D_;
  float s = 0.0f;
  for (int t = 0; t < D_ / 64; ++t) s = fmaf(qr[lane + (t << 6)], kr[lane + (t << 6)], s);
  for (int m = 1; m < 64; m <<= 1) s += __shfl_xor(s, m);
  if (lane == 0) diag[row] = __expf(s - mfin[row]) / lfin[row];
}

// ---------------- Kernel C: per-batch top-100 of diag, sorted ascending ----
__global__ __launch_bounds__(256) void top100_kernel(
    const float* __restrict__ diag, int* __restrict__ inst_idx) {
  __shared__ float sval[N_];
  __shared__ int sidx[N_];
  __shared__ int top[128];
  int b = blockIdx.x, tid = threadIdx.x;
  for (int i = tid; i < N_; i += 256) { sval[i] = diag[(size_t)b * N_ + i]; sidx[i] = i; }
  __syncthreads();
  // bitonic sort: value descending, tie -> lower index first (lax.top_k order)
  for (int ksz = 2; ksz <= N_; ksz <<= 1) {
    for (int j = ksz >> 1; j > 0; j >>= 1) {
      for (int t = tid; t < N_; t += 256) {
        int x = t ^ j;
        if (x > t) {
          float va = sval[t], vb = sval[x];
          int ia = sidx[t], ib = sidx[x];
          bool agtb = (va > vb) || (va == vb && ia < ib);
          bool up = ((t & ksz) == 0);
          if (up != agtb) { sval[t] = vb; sval[x] = va; sidx[t] = ib; sidx[x] = ia; }
        }
      }
      __syncthreads();
    }
  }
  if (tid < 128) top[tid] = (tid < KTOP) ? sidx[tid] : 0x7FFFFFFF;
  __syncthreads();
  // sort the 100 winners' indices ascending (bitonic over 128 with +inf pad)
  for (int ksz = 2; ksz <= 128; ksz <<= 1) {
    for (int j = ksz >> 1; j > 0; j >>= 1) {
      if (tid < 128) {
        int t = tid, x = t ^ j;
        if (x > t) {
          int ia = top[t], ib = top[x];
          bool up = ((t & ksz) == 0);
          bool altb = ia < ib;
          if (up != altb) { top[t] = ib; top[x] = ia; }
        }
      }
      __syncthreads();
    }
  }
  if (tid < KTOP) inst_idx[b * KTOP + tid] = top[tid];
}

// ---------------- Kernel D: rel 100x100, mask diag, top-5 per row ----------
__global__ __launch_bounds__(256) void reltop_kernel(
    const float* __restrict__ q, const float* __restrict__ k,
    const float* __restrict__ mfin, const float* __restrict__ lfin,
    const int* __restrict__ inst_idx, float* __restrict__ out0,
    int* __restrict__ pairs) {
  __shared__ int inst[KTOP];
  __shared__ float qv[D_];
  __shared__ float sv[KTOP];
  int a = blockIdx.x, b = blockIdx.y, tid = threadIdx.x;
  if (tid < KTOP) inst[tid] = inst_idx[b * KTOP + tid];
  __syncthreads();
  int ia = inst[a];
  const float* qrow = q + ((size_t)b * N_ + ia) * D_;
  for (int t = tid; t < D_; t += 256) qv[t] = qrow[t];
  __syncthreads();
  int wave = tid >> 6, lane = tid & 63;
  for (int c0 = 0; c0 < KTOP; c0 += 4) {
    int c = c0 + wave;
    const float* krow = k + ((size_t)b * N_ + inst[c]) * D_;
    float s = 0.0f;
    for (int t = 0; t < D_ / 64; ++t) s = fmaf(qv[lane + (t << 6)], krow[lane + (t << 6)], s);
    for (int m = 1; m < 64; m <<= 1) s += __shfl_xor(s, m);
    if (lane == 0) sv[c] = s;
  }
  __syncthreads();
  if (tid < 64) {
    float mi = mfin[(size_t)b * N_ + ia];
    float li = lfin[(size_t)b * N_ + ia];
    float c0v = (tid == a) ? 1e9f : __expf(sv[tid] - mi) / li;
    int c0i = tid;
    float c1v = -1.0f;
    int c1i = 1 << 20;
    if (tid + 64 < KTOP) {
      c1v = (tid + 64 == a) ? 1e9f : __expf(sv[tid + 64] - mi) / li;
      c1i = tid + 64;
    }
    int sel[RTOP];
    for (int rr = 0; rr < RTOP; ++rr) {
      float v;
      int idx;
      if (c1v > c0v || (c1v == c0v && c1i < c0i)) { v = c1v; idx = c1i; }
      else { v = c0v; idx = c0i; }
      for (int m = 1; m < 64; m <<= 1) {
        float ov = __shfl_xor(v, m);
        int oi = __shfl_xor(idx, m);
        if (ov > v || (ov == v && oi < idx)) { v = ov; idx = oi; }
      }
      sel[rr] = idx;
      if (idx == c0i) c0v = -2.0f;
      if (idx == c1i) c1v = -2.0f;
    }
    if (lane == 0) {
      for (int i2 = 0; i2 < RTOP; ++i2)
        for (int j2 = 0; j2 < RTOP - 1 - i2; ++j2)
          if (sel[j2] > sel[j2 + 1]) { int tswap = sel[j2]; sel[j2] = sel[j2 + 1]; sel[j2 + 1] = tswap; }
      for (int rr = 0; rr < RTOP; ++rr) {
        size_t ri = (size_t)b * KTOP * RTOP + (size_t)a * RTOP + rr;
        out0[ri * 3 + 0] = (float)b;
        out0[ri * 3 + 1] = (float)ia;
        out0[ri * 3 + 2] = (float)inst[sel[rr]];
        pairs[ri * 2 + 0] = ia;
        pairs[ri * 2 + 1] = inst[sel[rr]];
      }
    }
  }
}

// ---------------- Kernel E: gather + add + LayerNorm -----------------------
__global__ __launch_bounds__(256) void embed_kernel(
    const float* __restrict__ q, const int* __restrict__ pairs,
    float* __restrict__ out1) {
  __shared__ float red[8];
  int r = blockIdx.x, b = blockIdx.y, tid = threadIdx.x;
  size_t ri = (size_t)b * KTOP * RTOP + r;
  int subj = pairs[ri * 2 + 0], obj = pairs[ri * 2 + 1];
  const float* qs = q + ((size_t)b * N_ + subj) * D_;
  const float* qo = q + ((size_t)b * N_ + obj) * D_;
  float4 v1 = *(const float4*)(qs + tid * 4);
  float4 v2 = *(const float4*)(qo + tid * 4);
  float x0 = v1.x + v2.x, x1 = v1.y + v2.y, x2 = v1.z + v2.z, x3 = v1.w + v2.w;
  float s = x0 + x1 + x2 + x3;
  float qq = x0 * x0 + x1 * x1 + x2 * x2 + x3 * x3;
  int lane = tid & 63, wave = tid >> 6;
  for (int m = 1; m < 64; m <<= 1) { s += __shfl_xor(s, m); qq += __shfl_xor(qq, m); }
  if (lane == 0) { red[wave] = s; red[4 + wave] = qq; }
  __syncthreads();
  float S = red[0] + red[1] + red[2] + red[3];
  float Q = red[4] + red[5] + red[6] + red[7];
  float mu = S * (1.0f / D_);
  float var = Q * (1.0f / D_) - mu * mu;
  float rstd = 1.0f / sqrtf(var + 1e-5f);
  float4 o;
  o.x = (x0 - mu) * rstd;
  o.y = (x1 - mu) * rstd;
  o.z = (x2 - mu) * rstd;
  o.w = (x3 - mu) * rstd;
  *(float4*)(out1 + ri * D_ + tid * 4) = o;
}

extern "C" void kernel_launch(void* const* d_in, const int* in_sizes, int n_in,
                              void* d_out, int out_size, void* d_ws, size_t ws_size,
                              hipStream_t stream) {
  (void)in_sizes; (void)n_in; (void)out_size; (void)ws_size;
  const float* q = (const float*)d_in[0];
  const float* k = (const float*)d_in[1];
  float* out = (float*)d_out;

  char* ws = (char*)d_ws;
  float* mpart = (float*)ws; ws += (size_t)B_ * JCH * N_ * 4;
  float* lpart = (float*)ws; ws += (size_t)B_ * JCH * N_ * 4;
  float* mfin = (float*)ws;  ws += (size_t)B_ * N_ * 4;
  float* lfin = (float*)ws;  ws += (size_t)B_ * N_ * 4;
  float* diag = (float*)ws;  ws += (size_t)B_ * N_ * 4;
  int* inst = (int*)ws;      ws += (size_t)B_ * KTOP * 4;
  int* pairs = (int*)ws;     // B_*KTOP*RTOP*2 ints

  hipLaunchKernelGGL(rowstats_mfma, dim3(N_ / 128, N_ / 128, B_), dim3(256), 0, stream,
                     q, k, mpart, lpart);
  hipLaunchKernelGGL(combine_kernel, dim3(B_ * N_ / 256), dim3(256), 0, stream,
                     mpart, lpart, mfin, lfin);
  hipLaunchKernelGGL(diag_kernel, dim3(B_ * N_ / 4), dim3(256), 0, stream,
                     q, k, mfin, lfin, diag);
  hipLaunchKernelGGL(top100_kernel, dim3(B_), dim3(256), 0, stream, diag, inst);
  hipLaunchKernelGGL(reltop_kernel, dim3(KTOP, B_), dim3(256), 0, stream,
                     q, k, mfin, lfin, inst, out, pairs);
  hipLaunchKernelGGL(embed_kernel, dim3(KTOP * RTOP, B_), dim3(256), 0, stream,
                     q, pairs, out + (size_t)B_ * KTOP * RTOP * 3);
}

// Round 9
// 994.990 us; speedup vs baseline: 1.9006x; 1.1058x over previous
//
#include <hip/hip_runtime.h>
#include <math.h>

#define B_ 16
#define N_ 2048
#define D_ 1024
#define KTOP 100
#define RTOP 5
#define JCH 16

typedef __attribute__((ext_vector_type(8))) short short8;
typedef __attribute__((ext_vector_type(4))) float f32x4;

__device__ inline unsigned cvt_pk_bf16(float lo, float hi) {
  unsigned r;
  asm("v_cvt_pk_bf16_f32 %0, %1, %2" : "=v"(r) : "v"(lo), "v"(hi));
  return r;
}
__device__ inline float lo_bf(unsigned p) { return __uint_as_float(p << 16); }
__device__ inline float hi_bf(unsigned p) { return __uint_as_float(p & 0xFFFF0000u); }

// ---------------- Kernel A: MFMA row stats (m, l) over s = q k^T -----------
// 2-way bf16 split per operand (h+m), 4 MFMA products -> s error ~1e-4
// (rank-gap at diag top-100 boundary ~0.15 => flip risk ~2%, accepted).
// 128x128 tile per block; 4 waves, each 32 rows x 128 cols. LDS 32 KB.
__global__ __launch_bounds__(256) void rowstats_mfma(
    const float* __restrict__ q, const float* __restrict__ k,
    float* __restrict__ mpart, float* __restrict__ lpart) {
  __shared__ short Ah[128 * 32], Am[128 * 32];
  __shared__ short Bh[128 * 32], Bm[128 * 32];
  const int tid = threadIdx.x;
  const int wave = tid >> 6, lane = tid & 63;
  const int b = blockIdx.z;
  const int rb = blockIdx.x;   // row block (q)
  const int cb = blockIdx.y;   // col block (k) == j-chunk
  const float* qb = q + ((size_t)b * N_ + rb * 128) * D_;
  const float* kb = k + ((size_t)b * N_ + cb * 128) * D_;

  // staging role: threads 0-127 stage q rows, 128-255 stage k rows
  const int srow = tid & 127;
  const float* sbase = ((tid < 128) ? qb : kb) + (size_t)srow * D_;
  short* dsth = (tid < 128) ? Ah : Bh;
  short* dstm = (tid < 128) ? Am : Bm;
  const int swz = (srow >> 1) & 3;

  f32x4 acc[2][8];
#pragma unroll
  for (int fr = 0; fr < 2; ++fr)
#pragma unroll
    for (int fc = 0; fc < 8; ++fc)
#pragma unroll
      for (int r = 0; r < 4; ++r) acc[fr][fc][r] = 0.0f;

  const int g = lane >> 4;      // K slot group (8 bf16 = 16B)
  const int rlo = lane & 15;    // token row within fragment

  for (int kt = 0; kt < D_ / 32; ++kt) {
    __syncthreads();  // previous tile fully consumed
    // ---- stage: load 32 f32 of this row's K-window, 2-way split to LDS ----
    {
      const float* src = sbase + kt * 32;
#pragma unroll
      for (int j = 0; j < 4; ++j) {
        float4 ta = ((const float4*)src)[2 * j];
        float4 tb = ((const float4*)src)[2 * j + 1];
        // level h
        unsigned h0 = cvt_pk_bf16(ta.x, ta.y);
        unsigned h1 = cvt_pk_bf16(ta.z, ta.w);
        unsigned h2 = cvt_pk_bf16(tb.x, tb.y);
        unsigned h3 = cvt_pk_bf16(tb.z, tb.w);
        // residual r = x - h  (exact)
        float r0 = ta.x - lo_bf(h0), r1 = ta.y - hi_bf(h0);
        float r2 = ta.z - lo_bf(h1), r3 = ta.w - hi_bf(h1);
        float r4 = tb.x - lo_bf(h2), r5 = tb.y - hi_bf(h2);
        float r6 = tb.z - lo_bf(h3), r7 = tb.w - hi_bf(h3);
        // level m
        unsigned m0 = cvt_pk_bf16(r0, r1);
        unsigned m1 = cvt_pk_bf16(r2, r3);
        unsigned m2 = cvt_pk_bf16(r4, r5);
        unsigned m3 = cvt_pk_bf16(r6, r7);
        const int off = srow * 32 + ((j ^ swz) << 3);
        *(int4*)(dsth + off) = make_int4(h0, h1, h2, h3);
        *(int4*)(dstm + off) = make_int4(m0, m1, m2, m3);
      }
    }
    __syncthreads();  // tile ready
    // ---- compute: 2 row-frags x 8 col-frags x 4 products ----
    short8 afh[2], afm[2];
#pragma unroll
    for (int fr = 0; fr < 2; ++fr) {
      const int R = (wave << 5) + (fr << 4) + rlo;
      const int off = R * 32 + ((g ^ ((R >> 1) & 3)) << 3);
      afh[fr] = *(const short8*)&Ah[off];
      afm[fr] = *(const short8*)&Am[off];
    }
#pragma unroll
    for (int fc = 0; fc < 8; ++fc) {
      const int Rb = (fc << 4) + rlo;
      const int offb = Rb * 32 + ((g ^ ((Rb >> 1) & 3)) << 3);
      short8 bh = *(const short8*)&Bh[offb];
      short8 bm = *(const short8*)&Bm[offb];
#pragma unroll
      for (int fr = 0; fr < 2; ++fr) {
        acc[fr][fc] = __builtin_amdgcn_mfma_f32_16x16x32_bf16(afh[fr], bh, acc[fr][fc], 0, 0, 0);
        acc[fr][fc] = __builtin_amdgcn_mfma_f32_16x16x32_bf16(afh[fr], bm, acc[fr][fc], 0, 0, 0);
        acc[fr][fc] = __builtin_amdgcn_mfma_f32_16x16x32_bf16(afm[fr], bh, acc[fr][fc], 0, 0, 0);
        acc[fr][fc] = __builtin_amdgcn_mfma_f32_16x16x32_bf16(afm[fr], bm, acc[fr][fc], 0, 0, 0);
      }
    }
  }

  // ---- epilogue: per-row max & exp-sum over this 128-col chunk ----
  // C/D layout: col = lane&15, row = (lane>>4)*4 + reg  (within 16x16 frag)
#pragma unroll
  for (int fr = 0; fr < 2; ++fr) {
#pragma unroll
    for (int r = 0; r < 4; ++r) {
      float vmax = acc[fr][0][r];
#pragma unroll
      for (int fc = 1; fc < 8; ++fc) vmax = fmaxf(vmax, acc[fr][fc][r]);
#pragma unroll
      for (int m = 1; m < 16; m <<= 1) vmax = fmaxf(vmax, __shfl_xor(vmax, m));
      float s = 0.0f;
#pragma unroll
      for (int fc = 0; fc < 8; ++fc) s += __expf(acc[fr][fc][r] - vmax);
#pragma unroll
      for (int m = 1; m < 16; m <<= 1) s += __shfl_xor(s, m);
      if ((lane & 15) == 0) {
        const int row = (wave << 5) + (fr << 4) + ((lane >> 4) << 2) + r;
        size_t o = ((size_t)b * JCH + cb) * N_ + rb * 128 + row;
        mpart[o] = vmax;
        lpart[o] = s;
      }
    }
  }
}

// ---------------- Kernel A2: combine partial (m,l) across j-chunks ---------
__global__ __launch_bounds__(256) void combine_kernel(
    const float* __restrict__ mpart, const float* __restrict__ lpart,
    float* __restrict__ mfin, float* __restrict__ lfin) {
  int r = blockIdx.x * 256 + threadIdx.x;
  int b = r >> 11;
  int i = r & (N_ - 1);
  float m = -INFINITY, l = 0.0f;
  for (int jc = 0; jc < JCH; ++jc) {
    size_t o = ((size_t)b * JCH + jc) * N_ + i;
    float mp = mpart[o], lp = lpart[o];
    float mn = fmaxf(m, mp);
    l = l * __expf(m - mn) + lp * __expf(mp - mn);
    m = mn;
  }
  mfin[r] = m;
  lfin[r] = l;
}

// ---------------- Kernel B: diagonal softmax values ------------------------
__global__ __launch_bounds__(256) void diag_kernel(
    const float* __restrict__ q, const float* __restrict__ k,
    const float* __restrict__ mfin, const float* __restrict__ lfin,
    float* __restrict__ diag) {
  int wave = threadIdx.x >> 6, lane = threadIdx.x & 63;
  int row = blockIdx.x * 4 + wave;  // 0 .. B_*N_-1
  int b = row >> 11, i = row & (N_ - 1);
  const float* qr = q + ((size_t)b * N_ + i) * D_;
  const float* kr = k + ((size_t)b * N_ + i) * D_;
  float s = 0.0f;
  for (int t = 0; t < D_ / 64; ++t) s = fmaf(qr[lane + (t << 6)], kr[lane + (t << 6)], s);
  for (int m = 1; m < 64; m <<= 1) s += __shfl_xor(s, m);
  if (lane == 0) diag[row] = __expf(s - mfin[row]) / lfin[row];
}

// ---------------- Kernel C: per-batch top-100 of diag, sorted ascending ----
__global__ __launch_bounds__(256) void top100_kernel(
    const float* __restrict__ diag, int* __restrict__ inst_idx) {
  __shared__ float sval[N_];
  __shared__ int sidx[N_];
  __shared__ int top[128];
  int b = blockIdx.x, tid = threadIdx.x;
  for (int i = tid; i < N_; i += 256) { sval[i] = diag[(size_t)b * N_ + i]; sidx[i] = i; }
  __syncthreads();
  // bitonic sort: value descending, tie -> lower index first (lax.top_k order)
  for (int ksz = 2; ksz <= N_; ksz <<= 1) {
    for (int j = ksz >> 1; j > 0; j >>= 1) {
      for (int t = tid; t < N_; t += 256) {
        int x = t ^ j;
        if (x > t) {
          float va = sval[t], vb = sval[x];
          int ia = sidx[t], ib = sidx[x];
          bool agtb = (va > vb) || (va == vb && ia < ib);
          bool up = ((t & ksz) == 0);
          if (up != agtb) { sval[t] = vb; sval[x] = va; sidx[t] = ib; sidx[x] = ia; }
        }
      }
      __syncthreads();
    }
  }
  if (tid < 128) top[tid] = (tid < KTOP) ? sidx[tid] : 0x7FFFFFFF;
  __syncthreads();
  // sort the 100 winners' indices ascending (bitonic over 128 with +inf pad)
  for (int ksz = 2; ksz <= 128; ksz <<= 1) {
    for (int j = ksz >> 1; j > 0; j >>= 1) {
      if (tid < 128) {
        int t = tid, x = t ^ j;
        if (x > t) {
          int ia = top[t], ib = top[x];
          bool up = ((t & ksz) == 0);
          bool altb = ia < ib;
          if (up != altb) { top[t] = ib; top[x] = ia; }
        }
      }
      __syncthreads();
    }
  }
  if (tid < KTOP) inst_idx[b * KTOP + tid] = top[tid];
}

// ---------------- Kernel D: rel 100x100, mask diag, top-5 per row ----------
__global__ __launch_bounds__(256) void reltop_kernel(
    const float* __restrict__ q, const float* __restrict__ k,
    const float* __restrict__ mfin, const float* __restrict__ lfin,
    const int* __restrict__ inst_idx, float* __restrict__ out0,
    int* __restrict__ pairs) {
  __shared__ int inst[KTOP];
  __shared__ float qv[D_];
  __shared__ float sv[KTOP];
  int a = blockIdx.x, b = blockIdx.y, tid = threadIdx.x;
  if (tid < KTOP) inst[tid] = inst_idx[b * KTOP + tid];
  __syncthreads();
  int ia = inst[a];
  const float* qrow = q + ((size_t)b * N_ + ia) * D_;
  for (int t = tid; t < D_; t += 256) qv[t] = qrow[t];
  __syncthreads();
  int wave = tid >> 6, lane = tid & 63;
  for (int c0 = 0; c0 < KTOP; c0 += 4) {
    int c = c0 + wave;
    const float* krow = k + ((size_t)b * N_ + inst[c]) * D_;
    float s = 0.0f;
    for (int t = 0; t < D_ / 64; ++t) s = fmaf(qv[lane + (t << 6)], krow[lane + (t << 6)], s);
    for (int m = 1; m < 64; m <<= 1) s += __shfl_xor(s, m);
    if (lane == 0) sv[c] = s;
  }
  __syncthreads();
  if (tid < 64) {
    float mi = mfin[(size_t)b * N_ + ia];
    float li = lfin[(size_t)b * N_ + ia];
    float c0v = (tid == a) ? 1e9f : __expf(sv[tid] - mi) / li;
    int c0i = tid;
    float c1v = -1.0f;
    int c1i = 1 << 20;
    if (tid + 64 < KTOP) {
      c1v = (tid + 64 == a) ? 1e9f : __expf(sv[tid + 64] - mi) / li;
      c1i = tid + 64;
    }
    int sel[RTOP];
    for (int rr = 0; rr < RTOP; ++rr) {
      float v;
      int idx;
      if (c1v > c0v || (c1v == c0v && c1i < c0i)) { v = c1v; idx = c1i; }
      else { v = c0v; idx = c0i; }
      for (int m = 1; m < 64; m <<= 1) {
        float ov = __shfl_xor(v, m);
        int oi = __shfl_xor(idx, m);
        if (ov > v || (ov == v && oi < idx)) { v = ov; idx = oi; }
      }
      sel[rr] = idx;
      if (idx == c0i) c0v = -2.0f;
      if (idx == c1i) c1v = -2.0f;
    }
    if (lane == 0) {
      for (int i2 = 0; i2 < RTOP; ++i2)
        for (int j2 = 0; j2 < RTOP - 1 - i2; ++j2)
          if (sel[j2] > sel[j2 + 1]) { int tswap = sel[j2]; sel[j2] = sel[j2 + 1]; sel[j2 + 1] = tswap; }
      for (int rr = 0; rr < RTOP; ++rr) {
        size_t ri = (size_t)b * KTOP * RTOP + (size_t)a * RTOP + rr;
        out0[ri * 3 + 0] = (float)b;
        out0[ri * 3 + 1] = (float)ia;
        out0[ri * 3 + 2] = (float)inst[sel[rr]];
        pairs[ri * 2 + 0] = ia;
        pairs[ri * 2 + 1] = inst[sel[rr]];
      }
    }
  }
}

// ---------------- Kernel E: gather + add + LayerNorm -----------------------
__global__ __launch_bounds__(256) void embed_kernel(
    const float* __restrict__ q, const int* __restrict__ pairs,
    float* __restrict__ out1) {
  __shared__ float red[8];
  int r = blockIdx.x, b = blockIdx.y, tid = threadIdx.x;
  size_t ri = (size_t)b * KTOP * RTOP + r;
  int subj = pairs[ri * 2 + 0], obj = pairs[ri * 2 + 1];
  const float* qs = q + ((size_t)b * N_ + subj) * D_;
  const float* qo = q + ((size_t)b * N_ + obj) * D_;
  float4 v1 = *(const float4*)(qs + tid * 4);
  float4 v2 = *(const float4*)(qo + tid * 4);
  float x0 = v1.x + v2.x, x1 = v1.y + v2.y, x2 = v1.z + v2.z, x3 = v1.w + v2.w;
  float s = x0 + x1 + x2 + x3;
  float qq = x0 * x0 + x1 * x1 + x2 * x2 + x3 * x3;
  int lane = tid & 63, wave = tid >> 6;
  for (int m = 1; m < 64; m <<= 1) { s += __shfl_xor(s, m); qq += __shfl_xor(qq, m); }
  if (lane == 0) { red[wave] = s; red[4 + wave] = qq; }
  __syncthreads();
  float S = red[0] + red[1] + red[2] + red[3];
  float Q = red[4] + red[5] + red[6] + red[7];
  float mu = S * (1.0f / D_);
  float var = Q * (1.0f / D_) - mu * mu;
  float rstd = 1.0f / sqrtf(var + 1e-5f);
  float4 o;
  o.x = (x0 - mu) * rstd;
  o.y = (x1 - mu) * rstd;
  o.z = (x2 - mu) * rstd;
  o.w = (x3 - mu) * rstd;
  *(float4*)(out1 + ri * D_ + tid * 4) = o;
}

extern "C" void kernel_launch(void* const* d_in, const int* in_sizes, int n_in,
                              void* d_out, int out_size, void* d_ws, size_t ws_size,
                              hipStream_t stream) {
  (void)in_sizes; (void)n_in; (void)out_size; (void)ws_size;
  const float* q = (const float*)d_in[0];
  const float* k = (const float*)d_in[1];
  float* out = (float*)d_out;

  char* ws = (char*)d_ws;
  float* mpart = (float*)ws; ws += (size_t)B_ * JCH * N_ * 4;
  float* lpart = (float*)ws; ws += (size_t)B_ * JCH * N_ * 4;
  float* mfin = (float*)ws;  ws += (size_t)B_ * N_ * 4;
  float* lfin = (float*)ws;  ws += (size_t)B_ * N_ * 4;
  float* diag = (float*)ws;  ws += (size_t)B_ * N_ * 4;
  int* inst = (int*)ws;      ws += (size_t)B_ * KTOP * 4;
  int* pairs = (int*)ws;     // B_*KTOP*RTOP*2 ints

  hipLaunchKernelGGL(rowstats_mfma, dim3(N_ / 128, N_ / 128, B_), dim3(256), 0, stream,
                     q, k, mpart, lpart);
  hipLaunchKernelGGL(combine_kernel, dim3(B_ * N_ / 256), dim3(256), 0, stream,
                     mpart, lpart, mfin, lfin);
  hipLaunchKernelGGL(diag_kernel, dim3(B_ * N_ / 4), dim3(256), 0, stream,
                     q, k, mfin, lfin, diag);
  hipLaunchKernelGGL(top100_kernel, dim3(B_), dim3(256), 0, stream, diag, inst);
  hipLaunchKernelGGL(reltop_kernel, dim3(KTOP, B_), dim3(256), 0, stream,
                     q, k, mfin, lfin, inst, out, pairs);
  hipLaunchKernelGGL(embed_kernel, dim3(KTOP * RTOP, B_), dim3(256), 0, stream,
                     q, pairs, out + (size_t)B_ * KTOP * RTOP * 3);
}